// Round 5
// baseline (173.371 us; speedup 1.0000x reference)
//
#include <hip/hip_runtime.h>
#include <hip/hip_bf16.h>
#include <stdint.h>

// Problem constants
#define B_  4
#define S_  1024
#define D_  1024
#define H_  16
#define HD_ 64

using f32x4  = __attribute__((ext_vector_type(4))) float;
using bf16x8 = __attribute__((ext_vector_type(8))) __bf16;
using bf16x4 = __attribute__((ext_vector_type(4))) __bf16;
using f32x4v = __attribute__((ext_vector_type(4))) float;

// ---------------------------------------------------------------------------
// global -> LDS direct load, 16B per lane. LDS dest must be wave-uniform base;
// HW writes lane i at base + i*16 (m104).
__device__ __forceinline__ void g2l16(const void* g, void* l) {
  using gp = const __attribute__((address_space(1))) unsigned int*;
  using lp = __attribute__((address_space(3))) unsigned int*;
  __builtin_amdgcn_global_load_lds((gp)(unsigned long long)g,
                                   (lp)(unsigned int)(unsigned long long)l,
                                   16, 0, 0);
}

// ---------------------------------------------------------------------------
// f32 -> bf16 conversion (vectorized, 4 elems/thread)
__global__ __launch_bounds__(256) void cvt_kernel(const float* __restrict__ in,
                                                  __bf16* __restrict__ out, int n) {
  int i = (blockIdx.x * 256 + threadIdx.x) * 4;
  if (i >= n) return;
  f32x4v v = *(const f32x4v*)(in + i);
  bf16x4 o;
  o[0] = (__bf16)v[0]; o[1] = (__bf16)v[1]; o[2] = (__bf16)v[2]; o[3] = (__bf16)v[3];
  *(bf16x4*)(out + i) = o;
}

// fused 4-weight cvt: blockIdx.y selects the weight (Wq,Wk,Wv -> Wqkv; Wo -> Wob)
__global__ __launch_bounds__(256)
void cvt4_kernel(const float* __restrict__ w0, const float* __restrict__ w1,
                 const float* __restrict__ w2, const float* __restrict__ w3,
                 __bf16* __restrict__ Wqkv, __bf16* __restrict__ Wob) {
  const int y = blockIdx.y;
  const float* src = (y == 0) ? w0 : (y == 1) ? w1 : (y == 2) ? w2 : w3;
  __bf16* dst = (y < 3) ? (Wqkv + (size_t)y * 1048576) : Wob;
  int i = (blockIdx.x * 256 + threadIdx.x) * 4;
  f32x4v v = *(const f32x4v*)(src + i);
  bf16x4 o;
  o[0] = (__bf16)v[0]; o[1] = (__bf16)v[1]; o[2] = (__bf16)v[2]; o[3] = (__bf16)v[3];
  *(bf16x4*)(dst + i) = o;
}

// num_masked per batch
__global__ __launch_bounds__(64) void nm_kernel(const unsigned char* __restrict__ m,
                                                int* __restrict__ nm) {
  int b = blockIdx.x, t = threadIdx.x;
  int s = 0;
  for (int i = t; i < S_; i += 64) s += (m[b * S_ + i] != 0) ? 1 : 0;
  #pragma unroll
  for (int k = 1; k < 64; k <<= 1) s += __shfl_xor(s, k);
  if (t == 0) nm[b] = s;
}

// ---------------------------------------------------------------------------
// NT GEMM: C[M,N] = A[M,K] * B[N,K]^T, bf16 in, f32 acc.
// 128x128 tile, BK=32, prefetch double-buffered LDS (one barrier per K-step),
// bank-conflict XOR swizzle applied source-side + read-side.
// VT: column-blocks >= 2048 (the V projection) are stored TRANSPOSED into
// Vt[b][h][d][s] (4 r-values = consecutive s -> one 8B store per frag-row).
template <bool OUT_BF16, bool VT>
__global__ __launch_bounds__(256)
void gemm_nt(const __bf16* __restrict__ A, const __bf16* __restrict__ Bm,
             void* __restrict__ Cv, __bf16* __restrict__ Vt, int N, int K) {
  __shared__ __bf16 sA[2][128 * 32];
  __shared__ __bf16 sB[2][128 * 32];
  const int tid = threadIdx.x;
  const int wv = tid >> 6, lane = tid & 63;
  const int row0 = blockIdx.y * 128, col0 = blockIdx.x * 128;
  const int wm = wv >> 1, wn = wv & 1;
  const int c0 = wv * 2, c1 = c0 + 1;
  const int srow = lane >> 2;                               // row within 16-row chunk
  const int scol = (((lane & 3) ^ ((lane >> 3) & 3))) * 8;  // swizzled source slot
  const __bf16* Ab = A + (size_t)(row0 + srow) * K + scol;
  const __bf16* Bb = Bm + (size_t)(col0 + srow) * K + scol;
  const int fr = lane & 15;
  const int fk = ((lane >> 4) ^ ((fr >> 1) & 3)) * 8;       // swizzled read col

  f32x4 acc[4][4] = {};

#define GSTAGE(buf, k0) do {                                              \
    g2l16(Ab + (size_t)(c0 * 16) * K + (k0), &sA[buf][c0 * 512]);         \
    g2l16(Ab + (size_t)(c1 * 16) * K + (k0), &sA[buf][c1 * 512]);         \
    g2l16(Bb + (size_t)(c0 * 16) * K + (k0), &sB[buf][c0 * 512]);         \
    g2l16(Bb + (size_t)(c1 * 16) * K + (k0), &sB[buf][c1 * 512]);         \
  } while (0)

  GSTAGE(0, 0);
  __syncthreads();
  int cur = 0;
  for (int k0 = 0; k0 < K; k0 += 32) {
    if (k0 + 32 < K) GSTAGE(cur ^ 1, k0 + 32);   // prefetch next tile

    bf16x8 af[4], bfr[4];
    #pragma unroll
    for (int m = 0; m < 4; ++m)
      af[m] = *(const bf16x8*)&sA[cur][(wm * 64 + m * 16 + fr) * 32 + fk];
    #pragma unroll
    for (int n = 0; n < 4; ++n)
      bfr[n] = *(const bf16x8*)&sB[cur][(wn * 64 + n * 16 + fr) * 32 + fk];

    #pragma unroll
    for (int m = 0; m < 4; ++m)
      #pragma unroll
      for (int n = 0; n < 4; ++n)
        acc[m][n] = __builtin_amdgcn_mfma_f32_16x16x32_bf16(af[m], bfr[n], acc[m][n], 0, 0, 0);

    __syncthreads();   // single barrier: drains prefetch vmcnt + protects buffers
    cur ^= 1;
  }
#undef GSTAGE

  const int g4 = (lane >> 4) * 4;
  if (VT && col0 >= 2048) {
    // transposed store into Vt[b][h][d][s]
    #pragma unroll
    for (int m = 0; m < 4; ++m) {
      const int row = row0 + wm * 64 + m * 16 + g4;   // = b*1024 + s (s%4==0)
      const int bq = row >> 10, s = row & 1023;
      #pragma unroll
      for (int n = 0; n < 4; ++n) {
        const int hd = col0 + wn * 64 + n * 16 + fr - 2048;  // h*64 + d
        bf16x4 ov;
        #pragma unroll
        for (int r = 0; r < 4; ++r) ov[r] = (__bf16)acc[m][n][r];
        *(bf16x4*)&Vt[(size_t)((bq * H_ + (hd >> 6)) * HD_ + (hd & 63)) * S_ + s] = ov;
      }
    }
  } else if (OUT_BF16) {
    __bf16* C = (__bf16*)Cv;
    #pragma unroll
    for (int m = 0; m < 4; ++m)
      #pragma unroll
      for (int n = 0; n < 4; ++n)
        #pragma unroll
        for (int r = 0; r < 4; ++r)
          C[(size_t)(row0 + wm * 64 + m * 16 + g4 + r) * N + col0 + wn * 64 + n * 16 + fr] =
              (__bf16)acc[m][n][r];
  } else {
    float* C = (float*)Cv;
    #pragma unroll
    for (int m = 0; m < 4; ++m)
      #pragma unroll
      for (int n = 0; n < 4; ++n)
        #pragma unroll
        for (int r = 0; r < 4; ++r)
          C[(size_t)(row0 + wm * 64 + m * 16 + g4 + r) * N + col0 + wn * 64 + n * 16 + fr] =
              acc[m][n][r];
  }
}

// ---------------------------------------------------------------------------
// RoPE + RMSNorm + q per-dim scale. Block = one (b,s).
// q is pre-scaled by LOG2E^2/8 * softplus so attention scores are log2-domain.
__global__ __launch_bounds__(256)
void rope_rms(const __bf16* __restrict__ QKV, __bf16* __restrict__ Qr,
              __bf16* __restrict__ Kr, const float* __restrict__ qsc,
              const float* __restrict__ ksc, const float* __restrict__ pds,
              const int* __restrict__ nm) {
  const int bs = blockIdx.x;
  const int b = bs >> 10, s = bs & 1023;
  const int t = threadIdx.x;
  const bool isK = t >= 128;
  const int t2 = t & 127;
  const int h = t2 >> 3, j = t2 & 7;

  const __bf16* src = QKV + (size_t)bs * 3072 + (isK ? 1024 : 0) + h * 64 + j * 8;
  bf16x8 xv = *(const bf16x8*)src;
  float f[8], of[8];
  #pragma unroll
  for (int i = 0; i < 8; ++i) f[i] = (float)xv[i];

  const float pos = (float)s - (float)nm[b];
  #pragma unroll
  for (int i = 0; i < 8; ++i) {
    const float other = __shfl_xor(f[i], 4);
    const float frc = (float)((j & 3) * 8 + i) * (1.0f / 32.0f);
    const float ang = pos * exp2f(frc * -13.287712379549449f); // 1/10000^frc
    float sn, cs;
    sincosf(ang, &sn, &cs);
    of[i] = (j & 4) ? (f[i] * cs + other * sn)
                    : (f[i] * cs - other * sn);
  }

  float ss = 0.f;
  #pragma unroll
  for (int i = 0; i < 8; ++i) ss += of[i] * of[i];
  ss += __shfl_xor(ss, 1);
  ss += __shfl_xor(ss, 2);
  ss += __shfl_xor(ss, 4);
  const float rn = rsqrtf(ss * (1.0f / 64.0f) + 1e-6f);

  const float* sc = isK ? ksc : qsc;
  bf16x8 ov;
  #pragma unroll
  for (int i = 0; i < 8; ++i) {
    const int d = j * 8 + i;
    float v = of[i] * rn * sc[d];
    if (!isK) v *= 0.26017112262570096f * log1pf(expf(pds[d])); // LOG2E^2/8 * softplus
    ov[i] = (__bf16)v;
  }
  __bf16* dst = (isK ? Kr : Qr) + ((size_t)(b * H_ + h) * S_ + s) * HD_ + j * 8;
  *(bf16x8*)dst = ov;
}

// ---------------------------------------------------------------------------
// Flash attention v5: BARRIER-FREE. K/V fragments read directly from global
// (L2-resident: 256KB per (b,h)) -- no LDS staging, no __syncthreads, waves
// fully independent. Swapped QK^T (S^T = K Q^T) keeps softmax in-lane
// (15 fmax + 2 shfl). Wave-private LDS only for the P^T round-trip (8KB).
// Defer-max (T13, THR=8): skip O rescale unless row-max grows > 8.
__global__ __launch_bounds__(256)
void attn_fwd(const __bf16* __restrict__ Qr, const __bf16* __restrict__ Kr,
              const __bf16* __restrict__ Vt, __bf16* __restrict__ Ob,
              const int* __restrict__ nm) {
  const int bid = blockIdx.x;
  const int qblk = 15 - (bid >> 6);      // longest blocks dispatch first
  const int bh = bid & 63;
  const int b = bh >> 4, h = bh & 15;
  const int q0 = qblk * 64;
  const int tid = threadIdx.x, wv = tid >> 6, lane = tid & 63;

  __shared__ unsigned int sP[4][16 * 32];   // per-wave P^T, [q=16][32 words]

  const size_t bhs = (size_t)(b * H_ + h);
  const __bf16* Qh = Qr + bhs * (S_ * HD_);
  const __bf16* Kh = Kr + bhs * (S_ * HD_);
  const __bf16* Vh = Vt + bhs * (HD_ * S_);

  const int fr = lane & 15, g = lane >> 4;
  const int qbase = q0 + wv * 16;
  const int q = qbase + fr;                 // this lane's q-row
  unsigned int* sPw = &sP[wv][0];
  const int swz = (fr & 7) << 2;            // sP word-XOR swizzle

  bf16x8 qf[2];
  #pragma unroll
  for (int ks = 0; ks < 2; ++ks)
    qf[ks] = *(const bf16x8*)&Qh[(size_t)q * HD_ + ks * 32 + g * 8];

  f32x4 oacc[4] = {};                       // O^T: row d = nd*16+g*4+r, col q
  float mrun = -3e38f, lrun = 0.f;
  const int nmb = nm[b];

  for (int kv0 = 0; kv0 <= q0; kv0 += 64) {
    // K fragments straight from global (L2 hit)
    bf16x8 kf[4][2];
    #pragma unroll
    for (int n = 0; n < 4; ++n)
      #pragma unroll
      for (int ks = 0; ks < 2; ++ks)
        kf[n][ks] = *(const bf16x8*)&Kh[(size_t)(kv0 + n * 16 + fr) * HD_ + ks * 32 + g * 8];

    // S^T = K Q^T : sacc[n][r] = S[q][kv0 + n*16 + g*4 + r]
    f32x4 sacc[4] = {};
    __builtin_amdgcn_s_setprio(1);
    #pragma unroll
    for (int n = 0; n < 4; ++n)
      #pragma unroll
      for (int ks = 0; ks < 2; ++ks)
        sacc[n] = __builtin_amdgcn_mfma_f32_16x16x32_bf16(kf[n][ks], qf[ks], sacc[n], 0, 0, 0);
    __builtin_amdgcn_s_setprio(0);

    // V fragments issued early: L2 latency hides under the softmax VALU chain
    bf16x8 vf[4][2];
    #pragma unroll
    for (int nd = 0; nd < 4; ++nd)
      #pragma unroll
      for (int ks = 0; ks < 2; ++ks)
        vf[nd][ks] = *(const bf16x8*)&Vh[(size_t)(nd * 16 + fr) * S_ + kv0 + ks * 32 + g * 8];

    // mask: valid iff q >= kv && kv >= nmb
    const bool fullv = (qbase >= kv0 + 63) && (kv0 >= nmb);
    if (!fullv) {
      #pragma unroll
      for (int n = 0; n < 4; ++n)
        #pragma unroll
        for (int r = 0; r < 4; ++r) {
          const int kv = kv0 + n * 16 + g * 4 + r;
          if (q < kv || kv < nmb) sacc[n][r] = -1e30f;
        }
    }

    // online softmax with defer-max: in-lane max, reduce over g (2 shfls)
    float pmax = sacc[0][0];
    #pragma unroll
    for (int n = 0; n < 4; ++n)
      #pragma unroll
      for (int r = 0; r < 4; ++r) pmax = fmaxf(pmax, sacc[n][r]);
    pmax = fmaxf(pmax, __shfl_xor(pmax, 16));
    pmax = fmaxf(pmax, __shfl_xor(pmax, 32));
    if (pmax > mrun + 8.f) {                 // rescale only on big growth
      const float scl = exp2f(mrun - pmax);
      lrun *= scl;
      #pragma unroll
      for (int nd = 0; nd < 4; ++nd)
        #pragma unroll
        for (int r = 0; r < 4; ++r) oacc[nd][r] *= scl;
      mrun = pmax;
    }
    float ls = 0.f;
    #pragma unroll
    for (int n = 0; n < 4; ++n)
      #pragma unroll
      for (int r = 0; r < 4; ++r) {
        const float p = exp2f(sacc[n][r] - mrun);   // bounded by 2^8
        sacc[n][r] = p;
        ls += p;
      }
    ls += __shfl_xor(ls, 16);
    ls += __shfl_xor(ls, 32);
    lrun += ls;

    // pack P^T -> wave-private LDS (b64 writes, XOR swizzle), reload as frags
    #pragma unroll
    for (int n = 0; n < 4; ++n) {
      union { unsigned int u; __bf16 hh[2]; } p0, p1;
      p0.hh[0] = (__bf16)sacc[n][0]; p0.hh[1] = (__bf16)sacc[n][1];
      p1.hh[0] = (__bf16)sacc[n][2]; p1.hh[1] = (__bf16)sacc[n][3];
      const unsigned long long pu =
          (unsigned long long)p0.u | ((unsigned long long)p1.u << 32);
      *(unsigned long long*)&sPw[fr * 32 + ((n * 8 + g * 2) ^ swz)] = pu;
    }
    bf16x8 pf[2];
    #pragma unroll
    for (int ks = 0; ks < 2; ++ks)
      pf[ks] = *(const bf16x8*)&sPw[fr * 32 + ((ks * 16 + g * 4) ^ swz)];

    // O^T += V^T P^T
    __builtin_amdgcn_s_setprio(1);
    #pragma unroll
    for (int nd = 0; nd < 4; ++nd)
      #pragma unroll
      for (int ks = 0; ks < 2; ++ks)
        oacc[nd] = __builtin_amdgcn_mfma_f32_16x16x32_bf16(vf[nd][ks], pf[ks], oacc[nd], 0, 0, 0);
    __builtin_amdgcn_s_setprio(0);
  }

  // normalize + write O row q (4 x 8B stores)
  const float inv = 1.0f / lrun;
  __bf16* orow = Ob + (size_t)(b * S_ + q) * D_ + h * HD_;
  #pragma unroll
  for (int nd = 0; nd < 4; ++nd) {
    bf16x4 ov;
    #pragma unroll
    for (int r = 0; r < 4; ++r) ov[r] = (__bf16)(oacc[nd][r] * inv);
    *(bf16x4*)&orow[nd * 16 + g * 4] = ov;
  }
}

// ---------------------------------------------------------------------------
extern "C" void kernel_launch(void* const* d_in, const int* in_sizes, int n_in,
                              void* d_out, int out_size, void* d_ws, size_t ws_size,
                              hipStream_t stream) {
  (void)in_sizes; (void)n_in; (void)out_size; (void)ws_size;
  const float* X  = (const float*)d_in[0];
  const unsigned char* pm = (const unsigned char*)d_in[1];
  const float* Wq = (const float*)d_in[2];
  const float* Wk = (const float*)d_in[3];
  const float* Wv = (const float*)d_in[4];
  const float* Wo = (const float*)d_in[5];
  const float* qs = (const float*)d_in[6];
  const float* ks = (const float*)d_in[7];
  const float* pd = (const float*)d_in[8];
  float* out = (float*)d_out;

  char* ws = (char*)d_ws;
  int*    nm   = (int*)ws;                               // [0, 256)
  __bf16* Wqkv = (__bf16*)(ws + 256);                    // 3072x1024
  __bf16* Wob  = (__bf16*)(ws + 256 + 6291456);          // 1024x1024
  __bf16* Xb   = (__bf16*)(ws + 8388864);                // 4096x1024
  __bf16* QKV  = (__bf16*)(ws + 16777472);               // 4096x3072 (V cols unused)
  __bf16* Krb  = (__bf16*)(ws + 41943296);               // [b,h,s,d]
  __bf16* Vtb  = (__bf16*)(ws + 50331904);               // [b,h,d,s]
  __bf16* Qrb  = Xb;                                     // alias
  __bf16* Obuf = QKV;                                    // alias

  cvt_kernel<<<4096, 256, 0, stream>>>(X, Xb, 4194304);
  cvt4_kernel<<<dim3(1024, 4), 256, 0, stream>>>(Wq, Wk, Wv, Wo, Wqkv, Wob);
  nm_kernel<<<4, 64, 0, stream>>>(pm, nm);

  // QKV = Xb @ Wqkv^T  (M=4096, N=3072, K=1024); V columns stored transposed
  gemm_nt<true, true><<<dim3(24, 32), 256, 0, stream>>>(Xb, Wqkv, QKV, Vtb, 3072, 1024);

  rope_rms<<<4096, 256, 0, stream>>>(QKV, Qrb, Krb, qs, ks, pd, nm);

  attn_fwd<<<1024, 256, 0, stream>>>(Qrb, Krb, Vtb, Obuf, nm);

  // out = Obuf @ Wo^T  (M=4096, N=1024, K=1024)
  gemm_nt<false, false><<<dim3(8, 32), 256, 0, stream>>>(Obuf, Wob, out, nullptr, 1024, 1024);
}

// Round 6
// 106.851 us; speedup vs baseline: 1.6226x; 1.6226x over previous
//
#include <hip/hip_runtime.h>
#include <hip/hip_bf16.h>
#include <stdint.h>

// Problem constants
#define B_  4
#define S_  1024
#define D_  1024
#define H_  16
#define HD_ 64

using f32x4  = __attribute__((ext_vector_type(4))) float;
using bf16x8 = __attribute__((ext_vector_type(8))) __bf16;
using bf16x4 = __attribute__((ext_vector_type(4))) __bf16;
using f32x4v = __attribute__((ext_vector_type(4))) float;

// ---------------------------------------------------------------------------
// global -> LDS direct load, 16B per lane. LDS dest must be wave-uniform base;
// HW writes lane i at base + i*16 (m104).
__device__ __forceinline__ void g2l16(const void* g, void* l) {
  using gp = const __attribute__((address_space(1))) unsigned int*;
  using lp = __attribute__((address_space(3))) unsigned int*;
  __builtin_amdgcn_global_load_lds((gp)(unsigned long long)g,
                                   (lp)(unsigned int)(unsigned long long)l,
                                   16, 0, 0);
}

// ---------------------------------------------------------------------------
// prep: fused f32->bf16 cvt of X (blocks 0..4095) and the 4 weights
// (blocks 4096..8191), plus num_masked (block 8192).
__global__ __launch_bounds__(256)
void prep_kernel(const float* __restrict__ X, const float* __restrict__ w0,
                 const float* __restrict__ w1, const float* __restrict__ w2,
                 const float* __restrict__ w3, const unsigned char* __restrict__ mask,
                 __bf16* __restrict__ Xb, __bf16* __restrict__ Wqkv,
                 __bf16* __restrict__ Wob, int* __restrict__ nm) {
  const int bid = blockIdx.x, tid = threadIdx.x;
  if (bid < 4096) {
    const int i = bid * 1024 + tid * 4;
    f32x4v v = *(const f32x4v*)(X + i);
    bf16x4 o;
    o[0] = (__bf16)v[0]; o[1] = (__bf16)v[1]; o[2] = (__bf16)v[2]; o[3] = (__bf16)v[3];
    *(bf16x4*)(Xb + i) = o;
  } else if (bid < 8192) {
    const int bid2 = bid - 4096;
    const int y = bid2 >> 10;
    const float* src = (y == 0) ? w0 : (y == 1) ? w1 : (y == 2) ? w2 : w3;
    __bf16* dst = (y < 3) ? (Wqkv + (size_t)y * 1048576) : Wob;
    const int i = (bid2 & 1023) * 1024 + tid * 4;
    f32x4v v = *(const f32x4v*)(src + i);
    bf16x4 o;
    o[0] = (__bf16)v[0]; o[1] = (__bf16)v[1]; o[2] = (__bf16)v[2]; o[3] = (__bf16)v[3];
    *(bf16x4*)(dst + i) = o;
  } else {
    // one wave per batch: wave w sums mask[w][:]
    const int b = tid >> 6, ln = tid & 63;
    int s = 0;
    for (int i = ln; i < S_; i += 64) s += (mask[b * S_ + i] != 0) ? 1 : 0;
    #pragma unroll
    for (int k = 1; k < 64; k <<= 1) s += __shfl_xor(s, k);
    if (ln == 0) nm[b] = s;
  }
}

// ---------------------------------------------------------------------------
// NT GEMM: C[M,N] = A[M,K] * B[N,K]^T, bf16 in, f32 acc.
// 128x128 tile, BK=32, prefetch double-buffered LDS, XOR bank swizzle.
// MODE 0: plain f32 C store (output projection).
// MODE 1: QKV fused epilogue -- Q/K columns get RoPE + RMSNorm + per-dim
//   scale applied on the f32 accumulators and land in Qr/Kr[b,h,s,d];
//   V columns store transposed into Vt[b,h,d,s].
template <int MODE>
__global__ __launch_bounds__(256)
void gemm_nt(const __bf16* __restrict__ A, const __bf16* __restrict__ Bm,
             float* __restrict__ Cf, __bf16* __restrict__ Qr,
             __bf16* __restrict__ Kr, __bf16* __restrict__ Vt,
             const float* __restrict__ qsc, const float* __restrict__ ksc,
             const float* __restrict__ pds, const int* __restrict__ nm,
             int N, int K) {
  __shared__ __bf16 sA[2][128 * 32];
  __shared__ __bf16 sB[2][128 * 32];
  const int tid = threadIdx.x;
  const int wv = tid >> 6, lane = tid & 63;
  const int row0 = blockIdx.y * 128, col0 = blockIdx.x * 128;
  const int wm = wv >> 1, wn = wv & 1;
  const int c0 = wv * 2, c1 = c0 + 1;
  const int srow = lane >> 2;                               // row within 16-row chunk
  const int scol = (((lane & 3) ^ ((lane >> 3) & 3))) * 8;  // swizzled source slot
  const __bf16* Ab = A + (size_t)(row0 + srow) * K + scol;
  const __bf16* Bb = Bm + (size_t)(col0 + srow) * K + scol;
  const int fr = lane & 15;
  const int fk = ((lane >> 4) ^ ((fr >> 1) & 3)) * 8;       // swizzled read col

  f32x4 acc[4][4] = {};

#define GSTAGE(buf, k0) do {                                              \
    g2l16(Ab + (size_t)(c0 * 16) * K + (k0), &sA[buf][c0 * 512]);         \
    g2l16(Ab + (size_t)(c1 * 16) * K + (k0), &sA[buf][c1 * 512]);         \
    g2l16(Bb + (size_t)(c0 * 16) * K + (k0), &sB[buf][c0 * 512]);         \
    g2l16(Bb + (size_t)(c1 * 16) * K + (k0), &sB[buf][c1 * 512]);         \
  } while (0)

  GSTAGE(0, 0);
  __syncthreads();
  int cur = 0;
  for (int k0 = 0; k0 < K; k0 += 32) {
    if (k0 + 32 < K) GSTAGE(cur ^ 1, k0 + 32);   // prefetch next tile

    bf16x8 af[4], bfr[4];
    #pragma unroll
    for (int m = 0; m < 4; ++m)
      af[m] = *(const bf16x8*)&sA[cur][(wm * 64 + m * 16 + fr) * 32 + fk];
    #pragma unroll
    for (int n = 0; n < 4; ++n)
      bfr[n] = *(const bf16x8*)&sB[cur][(wn * 64 + n * 16 + fr) * 32 + fk];

    #pragma unroll
    for (int m = 0; m < 4; ++m)
      #pragma unroll
      for (int n = 0; n < 4; ++n)
        acc[m][n] = __builtin_amdgcn_mfma_f32_16x16x32_bf16(af[m], bfr[n], acc[m][n], 0, 0, 0);

    __syncthreads();   // single barrier: drains prefetch vmcnt + protects buffers
    cur ^= 1;
  }
#undef GSTAGE

  const int g4 = (lane >> 4) * 4;
  if (MODE == 0) {
    #pragma unroll
    for (int m = 0; m < 4; ++m)
      #pragma unroll
      for (int n = 0; n < 4; ++n)
        #pragma unroll
        for (int r = 0; r < 4; ++r)
          Cf[(size_t)(row0 + wm * 64 + m * 16 + g4 + r) * N + col0 + wn * 64 + n * 16 + fr] =
              acc[m][n][r];
    return;
  }

  // ---- MODE 1 epilogues ----
  if (col0 >= 2048) {
    // V: transposed store into Vt[b][h][d][s]
    #pragma unroll
    for (int m = 0; m < 4; ++m) {
      const int row = row0 + wm * 64 + m * 16 + g4;   // = b*1024 + s (s%4==0)
      const int bq = row >> 10, s = row & 1023;
      #pragma unroll
      for (int n = 0; n < 4; ++n) {
        const int hd = col0 + wn * 64 + n * 16 + fr - 2048;  // h*64 + d
        bf16x4 ov;
        #pragma unroll
        for (int r = 0; r < 4; ++r) ov[r] = (__bf16)acc[m][n][r];
        *(bf16x4*)&Vt[(size_t)((bq * H_ + (hd >> 6)) * HD_ + (hd & 63)) * S_ + s] = ov;
      }
    }
    return;
  }

  // Q/K: RoPE + RMSNorm + (Q) per-dim scale, write [b,h,s,d].
  // Lane owns dims d_n = n*16+fr; RoPE pairs (n0,n2) at freq fr, (n1,n3) at
  // freq 16+fr. Angles via complex-rotation recurrence (6 sincosf total).
  const bool isQ = col0 < 1024;
  const int head = ((col0 & 1023) >> 6) + wn;
  float scv[4];
  {
    const float* scp = isQ ? qsc : ksc;
    #pragma unroll
    for (int n = 0; n < 4; ++n) scv[n] = scp[n * 16 + fr];
    if (isQ) {
      #pragma unroll
      for (int n = 0; n < 4; ++n)
        scv[n] *= 0.26017112262570096f * log1pf(expf(pds[n * 16 + fr]));
    }
  }
  const int rowb = row0 + wm * 64;             // 64-aligned -> single b
  const int b = rowb >> 10;
  const int sbase = (rowb & 1023) + g4;        // + m*16 + r
  const float pos0 = (float)sbase - (float)nm[b];
  const float c13 = -0.41524101186092025f;     // -log2(10000)*... /32 in exp2 dom? (rad rate)
  // rate_d' = 10000^{-d'/32}: exp2f(d' * -13.2877.../32)
  const float e0 = exp2f((float)fr * c13);
  const float e1 = exp2f((float)(16 + fr) * c13);
  float zc0, zs0, zc1, zs1;                    // z = exp(i e pos0)
  __sincosf(pos0 * e0, &zs0, &zc0);
  zs0 = sinf(pos0 * e0); zc0 = cosf(pos0 * e0);
  zs1 = sinf(pos0 * e1); zc1 = cosf(pos0 * e1);
  float cw0[4], sw0[4], cw1[4], sw1[4];        // w^r, r=0..3
  cw0[0] = 1.f; sw0[0] = 0.f; cw1[0] = 1.f; sw1[0] = 0.f;
  sw0[1] = sinf(e0); cw0[1] = cosf(e0);
  sw1[1] = sinf(e1); cw1[1] = cosf(e1);
  cw0[2] = cw0[1]*cw0[1] - sw0[1]*sw0[1]; sw0[2] = 2.f*cw0[1]*sw0[1];
  cw1[2] = cw1[1]*cw1[1] - sw1[1]*sw1[1]; sw1[2] = 2.f*cw1[1]*sw1[1];
  cw0[3] = cw0[2]*cw0[1] - sw0[2]*sw0[1]; sw0[3] = sw0[2]*cw0[1] + cw0[2]*sw0[1];
  cw1[3] = cw1[2]*cw1[1] - sw1[2]*sw1[1]; sw1[3] = sw1[2]*cw1[1] + cw1[2]*sw1[1];
  float gc0, gs0, gc1, gs1;                    // w16 = exp(i 16 e)
  gs0 = sinf(16.f * e0); gc0 = cosf(16.f * e0);
  gs1 = sinf(16.f * e1); gc1 = cosf(16.f * e1);

  __bf16* base = (isQ ? Qr : Kr) + (size_t)(b * H_ + head) * (S_ * HD_);
  #pragma unroll
  for (int m = 0; m < 4; ++m) {
    #pragma unroll
    for (int r = 0; r < 4; ++r) {
      const float ca0 = zc0*cw0[r] - zs0*sw0[r], sa0 = zs0*cw0[r] + zc0*sw0[r];
      const float ca1 = zc1*cw1[r] - zs1*sw1[r], sa1 = zs1*cw1[r] + zc1*sw1[r];
      const float x0 = acc[m][0][r], x1 = acc[m][1][r];
      const float x2 = acc[m][2][r], x3 = acc[m][3][r];
      float o0 = x0*ca0 - x2*sa0;
      float o2 = x2*ca0 + x0*sa0;
      float o1 = x1*ca1 - x3*sa1;
      float o3 = x3*ca1 + x1*sa1;
      float ss = o0*o0 + o1*o1 + o2*o2 + o3*o3;
      ss += __shfl_xor(ss, 1);
      ss += __shfl_xor(ss, 2);
      ss += __shfl_xor(ss, 4);
      ss += __shfl_xor(ss, 8);
      const float rn = rsqrtf(ss * (1.0f / 64.0f) + 1e-6f);
      __bf16* dst = base + (size_t)(sbase + m * 16 + r) * HD_;
      dst[fr]      = (__bf16)(o0 * rn * scv[0]);
      dst[16 + fr] = (__bf16)(o1 * rn * scv[1]);
      dst[32 + fr] = (__bf16)(o2 * rn * scv[2]);
      dst[48 + fr] = (__bf16)(o3 * rn * scv[3]);
    }
    // z *= w16
    const float nc0 = zc0*gc0 - zs0*gs0; zs0 = zs0*gc0 + zc0*gs0; zc0 = nc0;
    const float nc1 = zc1*gc1 - zs1*gs1; zs1 = zs1*gc1 + zc1*gs1; zc1 = nc1;
  }
}

// ---------------------------------------------------------------------------
// Flash attention (round-4 structure): block = 64 q rows (4 waves x 16),
// grid 1024 (longest-first), K/V LDS-staged via global_load_lds with XOR
// swizzle, prefetch double-buffer, one barrier per tile. Swapped QK^T
// (S^T = K Q^T) keeps softmax in-lane; defer-max (T13, THR=8).
__global__ __launch_bounds__(256)
void attn_fwd(const __bf16* __restrict__ Qr, const __bf16* __restrict__ Kr,
              const __bf16* __restrict__ Vt, __bf16* __restrict__ Ob,
              const int* __restrict__ nm) {
  const int bid = blockIdx.x;
  const int qblk = 15 - (bid >> 6);      // longest blocks dispatch first
  const int bh = bid & 63;
  const int b = bh >> 4, h = bh & 15;
  const int q0 = qblk * 64;
  const int tid = threadIdx.x, wv = tid >> 6, lane = tid & 63;

  __shared__ __bf16 sK[2][64 * 64];
  __shared__ __bf16 sV[2][64 * 64];
  __shared__ unsigned int sP[4][16 * 32];   // per-wave P^T, [q=16][32 words]

  const size_t bhs = (size_t)(b * H_ + h);
  const __bf16* Qh = Qr + bhs * (S_ * HD_);
  const __bf16* Kh = Kr + bhs * (S_ * HD_);
  const __bf16* Vh = Vt + bhs * (HD_ * S_);

  const int fr = lane & 15, g = lane >> 4;
  const int qbase = q0 + wv * 16;
  const int q = qbase + fr;                 // this lane's q-row
  unsigned int* sPw = &sP[wv][0];
  const int swz = (fr & 7) << 2;            // sP word-XOR swizzle

  bf16x8 qf[2];
  #pragma unroll
  for (int ks = 0; ks < 2; ++ks)
    qf[ks] = *(const bf16x8*)&Qh[(size_t)q * HD_ + ks * 32 + g * 8];

  f32x4 oacc[4] = {};                       // O^T: row d = nd*16+g*4+r, col q
  float mrun = -3e38f, lrun = 0.f;

  const int nmb = nm[b];
  const int srow = lane >> 3;
  const int ssw = ((lane & 7) ^ srow) * 8;  // inverse-swizzled source col
  const int c0 = wv * 2, c1 = c0 + 1;

#define ASTAGE(buf, kv) do {                                                    \
    g2l16(&Kh[(size_t)((kv) + c0 * 8 + srow) * HD_ + ssw], &sK[buf][c0 * 512]); \
    g2l16(&Kh[(size_t)((kv) + c1 * 8 + srow) * HD_ + ssw], &sK[buf][c1 * 512]); \
    g2l16(&Vh[(size_t)(c0 * 8 + srow) * S_ + (kv) + ssw], &sV[buf][c0 * 512]);  \
    g2l16(&Vh[(size_t)(c1 * 8 + srow) * S_ + (kv) + ssw], &sV[buf][c1 * 512]);  \
  } while (0)

  ASTAGE(0, 0);
  __syncthreads();
  int cur = 0;
  const int kvend = q0 + 64;

  for (int kv0 = 0; kv0 < kvend; kv0 += 64) {
    if (kv0 + 64 < kvend) ASTAGE(cur ^ 1, kv0 + 64);   // prefetch next tile

    // S^T = K Q^T : sacc[n][r] = S[q][kv0 + n*16 + g*4 + r]
    f32x4 sacc[4] = {};
    __builtin_amdgcn_s_setprio(1);
    #pragma unroll
    for (int n = 0; n < 4; ++n) {
      const int krow = n * 16 + fr;
      #pragma unroll
      for (int ks = 0; ks < 2; ++ks) {
        bf16x8 kf = *(const bf16x8*)&sK[cur][krow * 64 + ((ks * 32 + g * 8) ^ ((krow & 7) * 8))];
        sacc[n] = __builtin_amdgcn_mfma_f32_16x16x32_bf16(kf, qf[ks], sacc[n], 0, 0, 0);
      }
    }
    __builtin_amdgcn_s_setprio(0);

    // mask: valid iff q >= kv && kv >= nmb (only the diagonal tile diverges)
    const bool fullv = (qbase >= kv0 + 63) && (kv0 >= nmb);
    if (!fullv) {
      #pragma unroll
      for (int n = 0; n < 4; ++n)
        #pragma unroll
        for (int r = 0; r < 4; ++r) {
          const int kv = kv0 + n * 16 + g * 4 + r;
          if (q < kv || kv < nmb) sacc[n][r] = -1e30f;
        }
    }

    // online softmax, defer-max: in-lane max + 2 shfls over g
    float pmax = sacc[0][0];
    #pragma unroll
    for (int n = 0; n < 4; ++n)
      #pragma unroll
      for (int r = 0; r < 4; ++r) pmax = fmaxf(pmax, sacc[n][r]);
    pmax = fmaxf(pmax, __shfl_xor(pmax, 16));
    pmax = fmaxf(pmax, __shfl_xor(pmax, 32));
    if (pmax > mrun + 8.f) {                 // rescale only on big growth
      const float scl = exp2f(mrun - pmax);
      lrun *= scl;
      #pragma unroll
      for (int nd = 0; nd < 4; ++nd)
        #pragma unroll
        for (int r = 0; r < 4; ++r) oacc[nd][r] *= scl;
      mrun = pmax;
    }
    float ls = 0.f;
    #pragma unroll
    for (int n = 0; n < 4; ++n)
      #pragma unroll
      for (int r = 0; r < 4; ++r) {
        const float p = exp2f(sacc[n][r] - mrun);   // bounded by 2^8
        sacc[n][r] = p;
        ls += p;
      }
    ls += __shfl_xor(ls, 16);
    ls += __shfl_xor(ls, 32);
    lrun += ls;

    // pack P^T -> wave-private LDS (b64 writes, XOR swizzle), reload as frags
    #pragma unroll
    for (int n = 0; n < 4; ++n) {
      union { unsigned int u; __bf16 hh[2]; } p0, p1;
      p0.hh[0] = (__bf16)sacc[n][0]; p0.hh[1] = (__bf16)sacc[n][1];
      p1.hh[0] = (__bf16)sacc[n][2]; p1.hh[1] = (__bf16)sacc[n][3];
      const unsigned long long pu =
          (unsigned long long)p0.u | ((unsigned long long)p1.u << 32);
      *(unsigned long long*)&sPw[fr * 32 + ((n * 8 + g * 2) ^ swz)] = pu;
    }
    bf16x8 pf[2];
    #pragma unroll
    for (int ks = 0; ks < 2; ++ks)
      pf[ks] = *(const bf16x8*)&sPw[fr * 32 + ((ks * 16 + g * 4) ^ swz)];

    // O^T += V^T P^T
    __builtin_amdgcn_s_setprio(1);
    #pragma unroll
    for (int nd = 0; nd < 4; ++nd) {
      const int vrow = nd * 16 + fr;
      #pragma unroll
      for (int ks = 0; ks < 2; ++ks) {
        bf16x8 vf = *(const bf16x8*)&sV[cur][vrow * 64 + ((ks * 32 + g * 8) ^ ((vrow & 7) * 8))];
        oacc[nd] = __builtin_amdgcn_mfma_f32_16x16x32_bf16(vf, pf[ks], oacc[nd], 0, 0, 0);
      }
    }
    __builtin_amdgcn_s_setprio(0);

    __syncthreads();   // single barrier: drains prefetch + protects buffers
    cur ^= 1;
  }
#undef ASTAGE

  // normalize + write O row q (4 x 8B stores)
  const float inv = 1.0f / lrun;
  __bf16* orow = Ob + (size_t)(b * S_ + q) * D_ + h * HD_;
  #pragma unroll
  for (int nd = 0; nd < 4; ++nd) {
    bf16x4 ov;
    #pragma unroll
    for (int r = 0; r < 4; ++r) ov[r] = (__bf16)(oacc[nd][r] * inv);
    *(bf16x4*)&orow[nd * 16 + g * 4] = ov;
  }
}

// ---------------------------------------------------------------------------
extern "C" void kernel_launch(void* const* d_in, const int* in_sizes, int n_in,
                              void* d_out, int out_size, void* d_ws, size_t ws_size,
                              hipStream_t stream) {
  (void)in_sizes; (void)n_in; (void)out_size; (void)ws_size;
  const float* X  = (const float*)d_in[0];
  const unsigned char* pm = (const unsigned char*)d_in[1];
  const float* Wq = (const float*)d_in[2];
  const float* Wk = (const float*)d_in[3];
  const float* Wv = (const float*)d_in[4];
  const float* Wo = (const float*)d_in[5];
  const float* qs = (const float*)d_in[6];
  const float* ks = (const float*)d_in[7];
  const float* pd = (const float*)d_in[8];
  float* out = (float*)d_out;

  char* ws = (char*)d_ws;
  int*    nm   = (int*)ws;                               // [0, 256)
  __bf16* Wqkv = (__bf16*)(ws + 256);                    // 3072x1024 (6MB)
  __bf16* Wob  = (__bf16*)(ws + 256 + 6291456);          // 1024x1024 (2MB)
  __bf16* Xb   = (__bf16*)(ws + 8388864);                // 4096x1024 (8MB)
  __bf16* Qrb  = (__bf16*)(ws + 16777472);               // [b,h,s,d] (8MB)
  __bf16* Obuf = (__bf16*)(ws + 16777472 + 8388608);     // [b,s,h*d] (8MB)
  __bf16* Krb  = (__bf16*)(ws + 41943296);               // [b,h,s,d] (8MB)
  __bf16* Vtb  = (__bf16*)(ws + 50331904);               // [b,h,d,s] (8MB)

  prep_kernel<<<8193, 256, 0, stream>>>(X, Wq, Wk, Wv, Wo, pm, Xb, Wqkv, Wob, nm);

  // QKV projection + fused RoPE/RMSNorm/scale epilogue + V transpose
  gemm_nt<1><<<dim3(24, 32), 256, 0, stream>>>(Xb, Wqkv, nullptr, Qrb, Krb, Vtb,
                                               qs, ks, pd, nm, 3072, 1024);

  attn_fwd<<<1024, 256, 0, stream>>>(Qrb, Krb, Vtb, Obuf, nm);

  // out = Obuf @ Wo^T  (M=4096, N=1024, K=1024)
  gemm_nt<0><<<dim3(8, 32), 256, 0, stream>>>(Obuf, Wob, out, nullptr, nullptr,
                                              nullptr, nullptr, nullptr, nullptr,
                                              nullptr, 1024, 1024);
}